// Round 1
// baseline (853.230 us; speedup 1.0000x reference)
//
#include <hip/hip_runtime.h>
#include <hip/hip_bf16.h>
#include <cstdint>

typedef __bf16 bf16_t;
typedef __bf16 bf16x8 __attribute__((ext_vector_type(8)));
typedef __bf16 bf16x4 __attribute__((ext_vector_type(4)));
typedef float f32x4 __attribute__((ext_vector_type(4)));

#define B_ 8
#define T_ 1024
#define C_ 768
#define H_ 12
#define D_ 64
#define NTOK 8192            // B*T
#define NHID_PAD 128
#define SCALE 0.03608439182435161f   // 768^-0.5
#define WEI_ELEMS 100663296ull       // 8*12*1024*1024

__device__ __forceinline__ f32x4 mfma16(bf16x8 a, bf16x8 b, f32x4 c) {
    return __builtin_amdgcn_mfma_f32_16x16x32_bf16(a, b, c, 0, 0, 0);
}

// ---------------------------------------------------------------- prep kernels
__global__ __launch_bounds__(256) void k_cast_x(const float* __restrict__ x,
                                                bf16_t* __restrict__ xb) {
    int i = blockIdx.x * 256 + threadIdx.x;          // 6144 blocks, exact
    const float4 v = reinterpret_cast<const float4*>(x)[i];
    bf16x4 o;
    o.x = (bf16_t)v.x; o.y = (bf16_t)v.y; o.z = (bf16_t)v.z; o.w = (bf16_t)v.w;
    *reinterpret_cast<bf16x4*>(xb + 4 * i) = o;
}

// Wqkv_t[(p*768 + h*64 + d)][c] = W{p}[h][c][d]   (2304 x 768)
__global__ __launch_bounds__(256) void k_pack_qkv(const float* __restrict__ Wq,
                                                  const float* __restrict__ Wk,
                                                  const float* __restrict__ Wv,
                                                  bf16_t* __restrict__ out) {
    int idx = blockIdx.x * 256 + threadIdx.x;        // 6912 blocks, exact
    int row = idx / C_, c = idx - row * C_;
    int p = row / C_;                                 // 0,1,2
    int hd = row - p * C_;
    int h = hd >> 6, d = hd & 63;
    const float* W = (p == 0) ? Wq : (p == 1 ? Wk : Wv);
    out[idx] = (bf16_t)W[((size_t)h * C_ + c) * D_ + d];
}

// Wproj_t[n][k] = Wproj[k][n]
__global__ __launch_bounds__(256) void k_pack_proj(const float* __restrict__ W,
                                                   bf16_t* __restrict__ out) {
    int idx = blockIdx.x * 256 + threadIdx.x;        // 2304 blocks, exact
    int n = idx / C_, k = idx - n * C_;
    out[idx] = (bf16_t)W[(size_t)k * C_ + n];
}

// W1t[128][768]: n<100 ? W1[k*100+n] : 0
__global__ __launch_bounds__(256) void k_pack_w1(const float* __restrict__ W,
                                                 bf16_t* __restrict__ out) {
    int idx = blockIdx.x * 256 + threadIdx.x;        // 384 blocks, exact
    int n = idx / C_, k = idx - n * C_;
    out[idx] = (bf16_t)((n < 100) ? W[(size_t)k * 100 + n] : 0.0f);
}

// W2t[768][128]: k<100 ? W2[k*768+n] : 0
__global__ __launch_bounds__(256) void k_pack_w2(const float* __restrict__ W,
                                                 bf16_t* __restrict__ out) {
    int idx = blockIdx.x * 256 + threadIdx.x;        // 384 blocks, exact
    int n = idx / NHID_PAD, k = idx & (NHID_PAD - 1);
    out[idx] = (bf16_t)((k < 100) ? W[(size_t)k * C_ + n] : 0.0f);
}

// ---------------------------------------------------------------- GEMM core
// C[M x N] = A[M x K] * B[N x K]^T ; block tile 128x128, BK=32, 4 waves of 64x64.
__device__ __forceinline__ void gemm_core(const bf16_t* __restrict__ A, int lda,
                                          const bf16_t* __restrict__ B, int ldb,
                                          int K, f32x4 acc[4][4]) {
    __shared__ __align__(16) bf16_t As[128 * 40];
    __shared__ __align__(16) bf16_t Bs[128 * 40];
    const int tid = threadIdx.x;
    const int wave = tid >> 6, lane = tid & 63;
    const int q = lane >> 4, ln = lane & 15;
    const int wm = (wave >> 1) * 64, wn = (wave & 1) * 64;
    const size_t bm = (size_t)blockIdx.y * 128, bn = (size_t)blockIdx.x * 128;

    const int lrow = tid >> 2;         // 0..63
    const int lkg = (tid & 3) * 8;     // 0,8,16,24

    const bf16_t* Ap0 = A + (bm + lrow) * lda + lkg;
    const bf16_t* Ap1 = A + (bm + lrow + 64) * lda + lkg;
    const bf16_t* Bp0 = B + (bn + lrow) * ldb + lkg;
    const bf16_t* Bp1 = B + (bn + lrow + 64) * ldb + lkg;
    bf16_t* As0 = &As[lrow * 40 + lkg];
    bf16_t* As1 = &As[(lrow + 64) * 40 + lkg];
    bf16_t* Bs0 = &Bs[lrow * 40 + lkg];
    bf16_t* Bs1 = &Bs[(lrow + 64) * 40 + lkg];

    for (int k0 = 0; k0 < K; k0 += 32) {
        bf16x8 a0 = *reinterpret_cast<const bf16x8*>(Ap0 + k0);
        bf16x8 a1 = *reinterpret_cast<const bf16x8*>(Ap1 + k0);
        bf16x8 b0 = *reinterpret_cast<const bf16x8*>(Bp0 + k0);
        bf16x8 b1 = *reinterpret_cast<const bf16x8*>(Bp1 + k0);
        __syncthreads();
        *reinterpret_cast<bf16x8*>(As0) = a0;
        *reinterpret_cast<bf16x8*>(As1) = a1;
        *reinterpret_cast<bf16x8*>(Bs0) = b0;
        *reinterpret_cast<bf16x8*>(Bs1) = b1;
        __syncthreads();
        bf16x8 af[4], bfr[4];
#pragma unroll
        for (int i = 0; i < 4; ++i)
            af[i] = *reinterpret_cast<const bf16x8*>(&As[(wm + i * 16 + ln) * 40 + q * 8]);
#pragma unroll
        for (int j = 0; j < 4; ++j)
            bfr[j] = *reinterpret_cast<const bf16x8*>(&Bs[(wn + j * 16 + ln) * 40 + q * 8]);
#pragma unroll
        for (int i = 0; i < 4; ++i)
#pragma unroll
            for (int j = 0; j < 4; ++j)
                acc[i][j] = mfma16(af[i], bfr[j], acc[i][j]);
    }
}

#define EPI_PROLOG                                              \
    const int lane = threadIdx.x & 63;                          \
    const int wave = threadIdx.x >> 6;                          \
    const int q = lane >> 4, ln = lane & 15;                    \
    const int row0 = blockIdx.y * 128 + (wave >> 1) * 64;       \
    const int col0 = blockIdx.x * 128 + (wave & 1) * 64;

// xb(8192x768) * Wqkv_t(q,k rows)(1536x768)^T -> scatter to qb/kb [b,h,t,d] bf16
__global__ __launch_bounds__(256) void k_gemm_qk(const bf16_t* __restrict__ A,
                                                 const bf16_t* __restrict__ Bm,
                                                 bf16_t* __restrict__ qb,
                                                 bf16_t* __restrict__ kb) {
    f32x4 acc[4][4] = {};
    gemm_core(A, C_, Bm, C_, C_, acc);
    EPI_PROLOG
#pragma unroll
    for (int i = 0; i < 4; ++i)
#pragma unroll
        for (int j = 0; j < 4; ++j)
#pragma unroll
            for (int r = 0; r < 4; ++r) {
                int grow = row0 + i * 16 + q * 4 + r;
                int gcol = col0 + j * 16 + ln;
                int p = (gcol >= C_) ? 1 : 0;
                int c = gcol - p * C_;
                int h = c >> 6, d = c & 63;
                int b = grow >> 10, t = grow & 1023;
                bf16_t* dst = p ? kb : qb;
                dst[(((size_t)b * H_ + h) * T_ + t) * D_ + d] = (bf16_t)acc[i][j][r];
            }
}

// Wv_t(768x768) * xb(8192x768)^T -> vt[b,h,d,t] bf16
__global__ __launch_bounds__(256) void k_gemm_vt(const bf16_t* __restrict__ A,
                                                 const bf16_t* __restrict__ Bm,
                                                 bf16_t* __restrict__ vt) {
    f32x4 acc[4][4] = {};
    gemm_core(A, C_, Bm, C_, C_, acc);
    EPI_PROLOG
#pragma unroll
    for (int i = 0; i < 4; ++i)
#pragma unroll
        for (int j = 0; j < 4; ++j)
#pragma unroll
            for (int r = 0; r < 4; ++r) {
                int grow = row0 + i * 16 + q * 4 + r;   // (h,d)
                int gcol = col0 + j * 16 + ln;          // (b,t)
                int h = grow >> 6, d = grow & 63;
                int b = gcol >> 10, t = gcol & 1023;
                vt[(((size_t)b * H_ + h) * D_ + d) * T_ + t] = (bf16_t)acc[i][j][r];
            }
}

// attn_cat(8192x768) * Wproj_t(768x768)^T + bproj -> proj fp32
__global__ __launch_bounds__(256) void k_gemm_proj(const bf16_t* __restrict__ A,
                                                   const bf16_t* __restrict__ Bm,
                                                   const float* __restrict__ bias,
                                                   float* __restrict__ out) {
    f32x4 acc[4][4] = {};
    gemm_core(A, C_, Bm, C_, C_, acc);
    EPI_PROLOG
#pragma unroll
    for (int i = 0; i < 4; ++i)
#pragma unroll
        for (int j = 0; j < 4; ++j)
#pragma unroll
            for (int r = 0; r < 4; ++r) {
                int grow = row0 + i * 16 + q * 4 + r;
                int gcol = col0 + j * 16 + ln;
                out[(size_t)grow * C_ + gcol] = acc[i][j][r] + bias[gcol];
            }
}

// hb(8192x768) * W1t(128x768)^T + b1, relu -> hid bf16 (ldc 128)
__global__ __launch_bounds__(256) void k_gemm_ff1(const bf16_t* __restrict__ A,
                                                  const bf16_t* __restrict__ Bm,
                                                  const float* __restrict__ bias,
                                                  bf16_t* __restrict__ out) {
    f32x4 acc[4][4] = {};
    gemm_core(A, C_, Bm, C_, C_, acc);
    EPI_PROLOG
#pragma unroll
    for (int i = 0; i < 4; ++i)
#pragma unroll
        for (int j = 0; j < 4; ++j)
#pragma unroll
            for (int r = 0; r < 4; ++r) {
                int grow = row0 + i * 16 + q * 4 + r;
                int gcol = col0 + j * 16 + ln;
                float v = acc[i][j][r] + ((gcol < 100) ? bias[gcol] : 0.0f);
                v = fmaxf(v, 0.0f);
                out[(size_t)grow * NHID_PAD + gcol] = (bf16_t)v;
            }
}

// hid(8192x128) * W2t(768x128)^T + b2 -> ff fp32
__global__ __launch_bounds__(256) void k_gemm_ff2(const bf16_t* __restrict__ A,
                                                  const bf16_t* __restrict__ Bm,
                                                  const float* __restrict__ bias,
                                                  float* __restrict__ out) {
    f32x4 acc[4][4] = {};
    gemm_core(A, NHID_PAD, Bm, NHID_PAD, NHID_PAD, acc);
    EPI_PROLOG
#pragma unroll
    for (int i = 0; i < 4; ++i)
#pragma unroll
        for (int j = 0; j < 4; ++j)
#pragma unroll
            for (int r = 0; r < 4; ++r) {
                int grow = row0 + i * 16 + q * 4 + r;
                int gcol = col0 + j * 16 + ln;
                out[(size_t)grow * C_ + gcol] = acc[i][j][r] + bias[gcol];
            }
}

// ---------------------------------------------------------------- fused attention
// One block per (b,h, 32-row Q block). QK^T -> softmax (exact wei to d_out) -> PV.
__global__ __launch_bounds__(256) void k_attn(const bf16_t* __restrict__ qb,
                                              const bf16_t* __restrict__ kb,
                                              const bf16_t* __restrict__ vt,
                                              float* __restrict__ wei,
                                              bf16_t* __restrict__ attn) {
    __shared__ __align__(16) bf16_t Qs[32 * 72];
    __shared__ __align__(16) bf16_t Ks[128 * 72];
    __shared__ __align__(16) bf16_t Vts[64 * 136];
    __shared__ __align__(16) bf16_t Sb[32 * 1032];

    const int tid = threadIdx.x;
    const int wave = tid >> 6, lane = tid & 63, q = lane >> 4, ln = lane & 15;
    const int bh = blockIdx.y;
    const int b = bh / H_, h = bh - b * H_;
    const int t0 = blockIdx.x * 32;
    const size_t bhbase = (size_t)bh * T_ * D_;

    // load Q block (32x64)
    {
        int r = tid >> 3, dg = (tid & 7) * 8;
        *reinterpret_cast<bf16x8*>(&Qs[r * 72 + dg]) =
            *reinterpret_cast<const bf16x8*>(qb + bhbase + (size_t)(t0 + r) * D_ + dg);
    }

    // ---- phase 2: S = Q K^T * scale -> Sb (bf16 logits)
    for (int st = 0; st < 8; ++st) {
        int s0 = st * 128;
#pragma unroll
        for (int u = 0; u < 4; ++u) {
            int l = u * 256 + tid;
            int r = l >> 3, dg = (l & 7) * 8;
            *reinterpret_cast<bf16x8*>(&Ks[r * 72 + dg]) =
                *reinterpret_cast<const bf16x8*>(kb + bhbase + (size_t)(s0 + r) * D_ + dg);
        }
        __syncthreads();
        f32x4 sacc[2][2] = {};
#pragma unroll
        for (int ks = 0; ks < 2; ++ks) {
            int ko = ks * 32 + q * 8;
            bf16x8 a0 = *reinterpret_cast<const bf16x8*>(&Qs[ln * 72 + ko]);
            bf16x8 a1 = *reinterpret_cast<const bf16x8*>(&Qs[(16 + ln) * 72 + ko]);
            bf16x8 b0 = *reinterpret_cast<const bf16x8*>(&Ks[(wave * 32 + ln) * 72 + ko]);
            bf16x8 b1 = *reinterpret_cast<const bf16x8*>(&Ks[(wave * 32 + 16 + ln) * 72 + ko]);
            sacc[0][0] = mfma16(a0, b0, sacc[0][0]);
            sacc[0][1] = mfma16(a0, b1, sacc[0][1]);
            sacc[1][0] = mfma16(a1, b0, sacc[1][0]);
            sacc[1][1] = mfma16(a1, b1, sacc[1][1]);
        }
#pragma unroll
        for (int i = 0; i < 2; ++i)
#pragma unroll
            for (int jj = 0; jj < 2; ++jj)
#pragma unroll
                for (int r = 0; r < 4; ++r) {
                    int row = i * 16 + q * 4 + r;
                    int col = s0 + wave * 32 + jj * 16 + ln;
                    Sb[row * 1032 + col] = (bf16_t)(sacc[i][jj][r] * SCALE);
                }
        __syncthreads();
    }

    // ---- softmax: wave owns rows [wave*8, wave*8+8)
    for (int rr = 0; rr < 8; ++rr) {
        int row = wave * 8 + rr;
        bf16_t* srow = &Sb[row * 1032];
        float vv[16];
        float mx = -1e30f;
#pragma unroll
        for (int jj = 0; jj < 16; ++jj) {
            vv[jj] = (float)srow[jj * 64 + lane];
            mx = fmaxf(mx, vv[jj]);
        }
#pragma unroll
        for (int off = 32; off; off >>= 1) mx = fmaxf(mx, __shfl_xor(mx, off));
        float sum = 0.0f;
#pragma unroll
        for (int jj = 0; jj < 16; ++jj) {
            vv[jj] = __expf(vv[jj] - mx);
            sum += vv[jj];
        }
#pragma unroll
        for (int off = 32; off; off >>= 1) sum += __shfl_xor(sum, off);
        float inv = 1.0f / sum;
        float* wrow = wei + ((size_t)bh << 20) + (size_t)(t0 + row) * T_;
#pragma unroll
        for (int jj = 0; jj < 16; ++jj) {
            float p = vv[jj] * inv;
            wrow[jj * 64 + lane] = p;
            srow[jj * 64 + lane] = (bf16_t)p;
        }
    }
    __syncthreads();

    // ---- phase 3: O = P V  (A = Sb probs, B^T = vt tile)
    f32x4 oacc[2] = {};
    const size_t vbase = (size_t)bh * D_ * T_;
    for (int st = 0; st < 8; ++st) {
        int s0 = st * 128;
#pragma unroll
        for (int u = 0; u < 4; ++u) {
            int l = u * 256 + tid;
            int d = l >> 4, sg = (l & 15) * 8;
            *reinterpret_cast<bf16x8*>(&Vts[d * 136 + sg]) =
                *reinterpret_cast<const bf16x8*>(vt + vbase + (size_t)d * T_ + s0 + sg);
        }
        __syncthreads();
#pragma unroll
        for (int ks = 0; ks < 4; ++ks) {
            int ko = ks * 32 + q * 8;
            bf16x8 b0 = *reinterpret_cast<const bf16x8*>(&Vts[(wave * 16 + ln) * 136 + ko]);
            bf16x8 a0 = *reinterpret_cast<const bf16x8*>(&Sb[ln * 1032 + s0 + ko]);
            bf16x8 a1 = *reinterpret_cast<const bf16x8*>(&Sb[(16 + ln) * 1032 + s0 + ko]);
            oacc[0] = mfma16(a0, b0, oacc[0]);
            oacc[1] = mfma16(a1, b0, oacc[1]);
        }
        __syncthreads();
    }
#pragma unroll
    for (int i = 0; i < 2; ++i)
#pragma unroll
        for (int r = 0; r < 4; ++r) {
            int trow = t0 + i * 16 + q * 4 + r;
            int col = h * D_ + wave * 16 + ln;
            attn[((size_t)b * T_ + trow) * C_ + col] = (bf16_t)oacc[i][r];
        }
}

// ---------------------------------------------------------------- layernorm
// out = LN(a_row + b_row) * g + beta ; writes fp32 (+optional bf16 copy)
__global__ __launch_bounds__(256) void k_ln(const float* __restrict__ a,
                                            const float* __restrict__ bsrc,
                                            const float* __restrict__ g,
                                            const float* __restrict__ beta,
                                            float* __restrict__ of,
                                            bf16_t* __restrict__ ob) {
    int row = blockIdx.x;
    int tid = threadIdx.x;
    const float* pa = a + (size_t)row * C_;
    const float* pb = bsrc + (size_t)row * C_;
    float v[3];
    float s = 0.0f, s2 = 0.0f;
#pragma unroll
    for (int u = 0; u < 3; ++u) {
        int c = tid + u * 256;
        v[u] = pa[c] + pb[c];
        s += v[u];
        s2 += v[u] * v[u];
    }
#pragma unroll
    for (int off = 32; off; off >>= 1) {
        s += __shfl_down(s, off);
        s2 += __shfl_down(s2, off);
    }
    __shared__ float ws[4], ws2[4];
    if ((tid & 63) == 0) { ws[tid >> 6] = s; ws2[tid >> 6] = s2; }
    __syncthreads();
    s = ws[0] + ws[1] + ws[2] + ws[3];
    s2 = ws2[0] + ws2[1] + ws2[2] + ws2[3];
    float mu = s * (1.0f / C_);
    float var = s2 * (1.0f / C_) - mu * mu;
    float ri = rsqrtf(var + 1e-5f);
#pragma unroll
    for (int u = 0; u < 3; ++u) {
        int c = tid + u * 256;
        float y = (v[u] - mu) * ri * g[c] + beta[c];
        of[(size_t)row * C_ + c] = y;
        if (ob) ob[(size_t)row * C_ + c] = (bf16_t)y;
    }
}

// ---------------------------------------------------------------- launch
extern "C" void kernel_launch(void* const* d_in, const int* in_sizes, int n_in,
                              void* d_out, int out_size, void* d_ws, size_t ws_size,
                              hipStream_t stream) {
    const float* x     = (const float*)d_in[0];
    const float* Wq    = (const float*)d_in[1];
    const float* Wk    = (const float*)d_in[2];
    const float* Wv    = (const float*)d_in[3];
    const float* Wproj = (const float*)d_in[4];
    const float* bproj = (const float*)d_in[5];
    const float* ln1g  = (const float*)d_in[6];
    const float* ln1b  = (const float*)d_in[7];
    const float* W1    = (const float*)d_in[8];
    const float* b1    = (const float*)d_in[9];
    const float* W2    = (const float*)d_in[10];
    const float* b2    = (const float*)d_in[11];
    const float* ln2g  = (const float*)d_in[12];
    const float* ln2b  = (const float*)d_in[13];

    char* ws = (char*)d_ws;
    // offsets (bytes); xb reused as hb, proj reused as ff
    bf16_t* xb     = (bf16_t*)(ws + 0);            // 12,582,912
    bf16_t* wqkvt  = (bf16_t*)(ws + 12582912);     //  3,538,944
    bf16_t* qbuf   = (bf16_t*)(ws + 16121856);     // 12,582,912
    bf16_t* kbuf   = (bf16_t*)(ws + 28704768);     // 12,582,912
    bf16_t* vtb    = (bf16_t*)(ws + 41287680);     // 12,582,912
    bf16_t* attnb  = (bf16_t*)(ws + 53870592);     // 12,582,912
    bf16_t* wprojt = (bf16_t*)(ws + 66453504);     //  1,179,648
    float*  projb  = (float*)(ws + 67633152);      // 25,165,824
    float*  hbuf   = (float*)(ws + 92798976);      // 25,165,824
    bf16_t* hidb   = (bf16_t*)(ws + 117964800);    //  2,097,152
    bf16_t* w1t    = (bf16_t*)(ws + 120061952);    //    196,608
    bf16_t* w2t    = (bf16_t*)(ws + 120258560);    //    196,608
    bf16_t* hbb    = xb;     // bf16 copy of h (xb dead after QKV GEMMs)
    float*  ffb    = projb;  // ff output (proj dead after LN1)

    float* wei = (float*)d_out;
    float* y   = (float*)d_out + WEI_ELEMS;

    k_cast_x<<<6144, 256, 0, stream>>>(x, xb);
    k_pack_qkv<<<6912, 256, 0, stream>>>(Wq, Wk, Wv, wqkvt);
    k_pack_proj<<<2304, 256, 0, stream>>>(Wproj, wprojt);
    k_pack_w1<<<384, 256, 0, stream>>>(W1, w1t);
    k_pack_w2<<<384, 256, 0, stream>>>(W2, w2t);

    k_gemm_qk<<<dim3(12, 64), 256, 0, stream>>>(xb, wqkvt, qbuf, kbuf);
    k_gemm_vt<<<dim3(64, 6), 256, 0, stream>>>(wqkvt + (size_t)1536 * C_, xb, vtb);

    k_attn<<<dim3(32, 96), 256, 0, stream>>>(qbuf, kbuf, vtb, wei, attnb);

    k_gemm_proj<<<dim3(6, 64), 256, 0, stream>>>(attnb, wprojt, bproj, projb);
    k_ln<<<8192, 256, 0, stream>>>(x, projb, ln1g, ln1b, hbuf, hbb);
    k_gemm_ff1<<<dim3(1, 64), 256, 0, stream>>>(hbb, w1t, b1, hidb);
    k_gemm_ff2<<<dim3(6, 64), 256, 0, stream>>>(hidb, w2t, b2, ffb);
    k_ln<<<8192, 256, 0, stream>>>(hbuf, ffb, ln2g, ln2b, y, (bf16_t*)nullptr);

    (void)in_sizes; (void)n_in; (void)out_size; (void)ws_size;
}

// Round 2
// 764.925 us; speedup vs baseline: 1.1154x; 1.1154x over previous
//
#include <hip/hip_runtime.h>
#include <hip/hip_bf16.h>
#include <cstdint>

typedef __bf16 bf16_t;
typedef __bf16 bf16x8 __attribute__((ext_vector_type(8)));
typedef __bf16 bf16x4 __attribute__((ext_vector_type(4)));
typedef float f32x4 __attribute__((ext_vector_type(4)));

#define B_ 8
#define T_ 1024
#define C_ 768
#define H_ 12
#define D_ 64
#define NTOK 8192            // B*T
#define NHID_PAD 128
#define SCALE 0.03608439182435161f   // 768^-0.5
#define WEI_ELEMS 100663296ull       // 8*12*1024*1024

__device__ __forceinline__ f32x4 mfma16(bf16x8 a, bf16x8 b, f32x4 c) {
    return __builtin_amdgcn_mfma_f32_16x16x32_bf16(a, b, c, 0, 0, 0);
}

// async global->LDS, 16B per lane. LDS dest = wave-uniform base + lane*16.
typedef const unsigned int __attribute__((address_space(1)))* gaddr_t;
typedef unsigned int __attribute__((address_space(3)))* laddr_t;
__device__ __forceinline__ void gload16(const bf16_t* g, bf16_t* l) {
    __builtin_amdgcn_global_load_lds((gaddr_t)g, (laddr_t)l, 16, 0, 0);
}

// ---------------------------------------------------------------- prep kernels
__global__ __launch_bounds__(256) void k_cast_x(const float* __restrict__ x,
                                                bf16_t* __restrict__ xb) {
    int i = blockIdx.x * 256 + threadIdx.x;          // 6144 blocks, exact
    const float4 v = reinterpret_cast<const float4*>(x)[i];
    bf16x4 o;
    o.x = (bf16_t)v.x; o.y = (bf16_t)v.y; o.z = (bf16_t)v.z; o.w = (bf16_t)v.w;
    *reinterpret_cast<bf16x4*>(xb + 4 * i) = o;
}

// Wqkv_t[(p*768 + h*64 + d)][c] = W{p}[h][c][d]   (2304 x 768)
__global__ __launch_bounds__(256) void k_pack_qkv(const float* __restrict__ Wq,
                                                  const float* __restrict__ Wk,
                                                  const float* __restrict__ Wv,
                                                  bf16_t* __restrict__ out) {
    int idx = blockIdx.x * 256 + threadIdx.x;        // 6912 blocks, exact
    int row = idx / C_, c = idx - row * C_;
    int p = row / C_;                                 // 0,1,2
    int hd = row - p * C_;
    int h = hd >> 6, d = hd & 63;
    const float* W = (p == 0) ? Wq : (p == 1 ? Wk : Wv);
    out[idx] = (bf16_t)W[((size_t)h * C_ + c) * D_ + d];
}

// Wproj_t[n][k] = Wproj[k][n]
__global__ __launch_bounds__(256) void k_pack_proj(const float* __restrict__ W,
                                                   bf16_t* __restrict__ out) {
    int idx = blockIdx.x * 256 + threadIdx.x;        // 2304 blocks, exact
    int n = idx / C_, k = idx - n * C_;
    out[idx] = (bf16_t)W[(size_t)k * C_ + n];
}

// W1t[128][768]: n<100 ? W1[k*100+n] : 0
__global__ __launch_bounds__(256) void k_pack_w1(const float* __restrict__ W,
                                                 bf16_t* __restrict__ out) {
    int idx = blockIdx.x * 256 + threadIdx.x;        // 384 blocks, exact
    int n = idx / C_, k = idx - n * C_;
    out[idx] = (bf16_t)((n < 100) ? W[(size_t)k * 100 + n] : 0.0f);
}

// W2t[768][128]: k<100 ? W2[k*768+n] : 0
__global__ __launch_bounds__(256) void k_pack_w2(const float* __restrict__ W,
                                                 bf16_t* __restrict__ out) {
    int idx = blockIdx.x * 256 + threadIdx.x;        // 384 blocks, exact
    int n = idx / NHID_PAD, k = idx & (NHID_PAD - 1);
    out[idx] = (bf16_t)((k < 100) ? W[(size_t)k * C_ + n] : 0.0f);
}

// ---------------------------------------------------------------- GEMM core
// C[M x N] = A[M x K] * B[N x K]^T ; block tile 128x128, BK=32, 4 waves.
// m97-style staging: global_load_lds width=16, unpadded 128x32 LDS tiles.
__device__ __forceinline__ void gemm_core(const bf16_t* __restrict__ A, int lda,
                                          const bf16_t* __restrict__ B, int ldb,
                                          int K, f32x4 acc[4][4]) {
    __shared__ __align__(16) bf16_t As[128 * 32];
    __shared__ __align__(16) bf16_t Bs[128 * 32];
    const int tid = threadIdx.x;
    const int wave = tid >> 6, lane = tid & 63;
    const int q = lane >> 4, ln = lane & 15;
    const int wm = (wave >> 1) * 64, wn = (wave & 1) * 64;
    const size_t bm = (size_t)blockIdx.y * 128, bn = (size_t)blockIdx.x * 128;

    // chunk c = wave*2+u covers LDS rows [c*16, c*16+16); lane i -> row c*16+i/4, col (i%4)*8
    const int c0 = wave * 2;
    const int srow = c0 * 16 + (lane >> 2);
    const int kg = (lane & 3) * 8;
    const bf16_t* Ap0 = A + (bm + srow) * lda + kg;
    const bf16_t* Ap1 = A + (bm + srow + 16) * lda + kg;
    const bf16_t* Bp0 = B + (bn + srow) * ldb + kg;
    const bf16_t* Bp1 = B + (bn + srow + 16) * ldb + kg;
    bf16_t* AsD0 = As + c0 * 512;          // wave-uniform LDS bases
    bf16_t* AsD1 = As + (c0 + 1) * 512;
    bf16_t* BsD0 = Bs + c0 * 512;
    bf16_t* BsD1 = Bs + (c0 + 1) * 512;

    for (int k0 = 0; k0 < K; k0 += 32) {
        __syncthreads();
        gload16(Ap0 + k0, AsD0);
        gload16(Ap1 + k0, AsD1);
        gload16(Bp0 + k0, BsD0);
        gload16(Bp1 + k0, BsD1);
        __syncthreads();
        bf16x8 af[4], bfr[4];
#pragma unroll
        for (int i = 0; i < 4; ++i)
            af[i] = *reinterpret_cast<const bf16x8*>(&As[(wm + i * 16 + ln) * 32 + q * 8]);
#pragma unroll
        for (int j = 0; j < 4; ++j)
            bfr[j] = *reinterpret_cast<const bf16x8*>(&Bs[(wn + j * 16 + ln) * 32 + q * 8]);
#pragma unroll
        for (int i = 0; i < 4; ++i)
#pragma unroll
            for (int j = 0; j < 4; ++j)
                acc[i][j] = mfma16(af[i], bfr[j], acc[i][j]);
    }
}

#define EPI_PROLOG                                              \
    const int lane = threadIdx.x & 63;                          \
    const int wave = threadIdx.x >> 6;                          \
    const int q = lane >> 4, ln = lane & 15;                    \
    const int row0 = blockIdx.y * 128 + (wave >> 1) * 64;       \
    const int col0 = blockIdx.x * 128 + (wave & 1) * 64;

// xb(8192x768) * Wqkv_t(q,k rows)(1536x768)^T -> scatter to qb/kb [b,h,t,d] bf16
__global__ __launch_bounds__(256) void k_gemm_qk(const bf16_t* __restrict__ A,
                                                 const bf16_t* __restrict__ Bm,
                                                 bf16_t* __restrict__ qb,
                                                 bf16_t* __restrict__ kb) {
    f32x4 acc[4][4] = {};
    gemm_core(A, C_, Bm, C_, C_, acc);
    EPI_PROLOG
#pragma unroll
    for (int i = 0; i < 4; ++i)
#pragma unroll
        for (int j = 0; j < 4; ++j)
#pragma unroll
            for (int r = 0; r < 4; ++r) {
                int grow = row0 + i * 16 + q * 4 + r;
                int gcol = col0 + j * 16 + ln;
                int p = (gcol >= C_) ? 1 : 0;
                int c = gcol - p * C_;
                int h = c >> 6, d = c & 63;
                int b = grow >> 10, t = grow & 1023;
                bf16_t* dst = p ? kb : qb;
                dst[(((size_t)b * H_ + h) * T_ + t) * D_ + d] = (bf16_t)acc[i][j][r];
            }
}

// Wv_t(768x768) * xb(8192x768)^T -> vt[b,h,d,t] bf16
__global__ __launch_bounds__(256) void k_gemm_vt(const bf16_t* __restrict__ A,
                                                 const bf16_t* __restrict__ Bm,
                                                 bf16_t* __restrict__ vt) {
    f32x4 acc[4][4] = {};
    gemm_core(A, C_, Bm, C_, C_, acc);
    EPI_PROLOG
#pragma unroll
    for (int i = 0; i < 4; ++i)
#pragma unroll
        for (int j = 0; j < 4; ++j)
#pragma unroll
            for (int r = 0; r < 4; ++r) {
                int grow = row0 + i * 16 + q * 4 + r;   // (h,d)
                int gcol = col0 + j * 16 + ln;          // (b,t)
                int h = grow >> 6, d = grow & 63;
                int b = gcol >> 10, t = gcol & 1023;
                vt[(((size_t)b * H_ + h) * D_ + d) * T_ + t] = (bf16_t)acc[i][j][r];
            }
}

// attn_cat(8192x768) * Wproj_t(768x768)^T + bproj -> proj fp32
__global__ __launch_bounds__(256) void k_gemm_proj(const bf16_t* __restrict__ A,
                                                   const bf16_t* __restrict__ Bm,
                                                   const float* __restrict__ bias,
                                                   float* __restrict__ out) {
    f32x4 acc[4][4] = {};
    gemm_core(A, C_, Bm, C_, C_, acc);
    EPI_PROLOG
#pragma unroll
    for (int i = 0; i < 4; ++i)
#pragma unroll
        for (int j = 0; j < 4; ++j)
#pragma unroll
            for (int r = 0; r < 4; ++r) {
                int grow = row0 + i * 16 + q * 4 + r;
                int gcol = col0 + j * 16 + ln;
                out[(size_t)grow * C_ + gcol] = acc[i][j][r] + bias[gcol];
            }
}

// hb(8192x768) * W1t(128x768)^T + b1, relu -> hid bf16 (ldc 128)
__global__ __launch_bounds__(256) void k_gemm_ff1(const bf16_t* __restrict__ A,
                                                  const bf16_t* __restrict__ Bm,
                                                  const float* __restrict__ bias,
                                                  bf16_t* __restrict__ out) {
    f32x4 acc[4][4] = {};
    gemm_core(A, C_, Bm, C_, C_, acc);
    EPI_PROLOG
#pragma unroll
    for (int i = 0; i < 4; ++i)
#pragma unroll
        for (int j = 0; j < 4; ++j)
#pragma unroll
            for (int r = 0; r < 4; ++r) {
                int grow = row0 + i * 16 + q * 4 + r;
                int gcol = col0 + j * 16 + ln;
                float v = acc[i][j][r] + ((gcol < 100) ? bias[gcol] : 0.0f);
                v = fmaxf(v, 0.0f);
                out[(size_t)grow * NHID_PAD + gcol] = (bf16_t)v;
            }
}

// hid(8192x128) * W2t(768x128)^T + b2 -> ff fp32
__global__ __launch_bounds__(256) void k_gemm_ff2(const bf16_t* __restrict__ A,
                                                  const bf16_t* __restrict__ Bm,
                                                  const float* __restrict__ bias,
                                                  float* __restrict__ out) {
    f32x4 acc[4][4] = {};
    gemm_core(A, NHID_PAD, Bm, NHID_PAD, NHID_PAD, acc);
    EPI_PROLOG
#pragma unroll
    for (int i = 0; i < 4; ++i)
#pragma unroll
        for (int j = 0; j < 4; ++j)
#pragma unroll
            for (int r = 0; r < 4; ++r) {
                int grow = row0 + i * 16 + q * 4 + r;
                int gcol = col0 + j * 16 + ln;
                out[(size_t)grow * C_ + gcol] = acc[i][j][r] + bias[gcol];
            }
}

// ---------------------------------------------------------------- fused attention
// One block per (b,h, 16 Q-rows). S lives entirely in MFMA accumulators:
// wave w owns key-columns [w*256, w*256+256) as 16 16x16 tiles (64 f32/lane).
// Q and K load from global directly in fragment layout (no LDS, no barriers).
// Softmax: shuffle reduce within 16-lane groups + 256B LDS cross-wave exchange.
// Only the normalized P tile (16x1024 bf16, 33KB) round-trips LDS for PV.
__global__ __launch_bounds__(256, 3) void k_attn(const bf16_t* __restrict__ qb,
                                                 const bf16_t* __restrict__ kb,
                                                 const bf16_t* __restrict__ vt,
                                                 float* __restrict__ wei,
                                                 bf16_t* __restrict__ attn) {
    __shared__ __align__(16) bf16_t Ps[16 * 1032];
    __shared__ float redm[4][16];
    __shared__ float reds[4][16];

    const int tid = threadIdx.x;
    const int w = tid >> 6, lane = tid & 63;
    const int qq = lane >> 4, ln = lane & 15;
    const int bh = blockIdx.y;
    const int b = bh / H_, h = bh - b * H_;
    const int t0 = blockIdx.x * 16;
    const size_t bhbase = (size_t)bh * (T_ * D_);

    // Q fragments (A-layout: lane -> row ln, k = qq*8+j)
    const bf16_t* qp = qb + bhbase + (size_t)(t0 + ln) * D_ + qq * 8;
    const bf16x8 aq0 = *reinterpret_cast<const bf16x8*>(qp);
    const bf16x8 aq1 = *reinterpret_cast<const bf16x8*>(qp + 32);

    // S = Q K^T : K loads directly in B-fragment layout (row s -> n=ln)
    f32x4 sacc[16] = {};
    const bf16_t* kp = kb + bhbase + (size_t)(w * 256 + ln) * D_ + qq * 8;
#pragma unroll
    for (int j = 0; j < 16; ++j) {
        bf16x8 b0 = *reinterpret_cast<const bf16x8*>(kp + j * 16 * D_);
        bf16x8 b1 = *reinterpret_cast<const bf16x8*>(kp + j * 16 * D_ + 32);
        sacc[j] = mfma16(aq0, b0, sacc[j]);
        sacc[j] = mfma16(aq1, b1, sacc[j]);
    }

    // row max (rows qq*4+r over this wave's 256 cols, then cross-wave)
    float mx[4];
#pragma unroll
    for (int r = 0; r < 4; ++r) {
        float m = sacc[0][r];
#pragma unroll
        for (int j = 1; j < 16; ++j) m = fmaxf(m, sacc[j][r]);
#pragma unroll
        for (int off = 1; off < 16; off <<= 1) m = fmaxf(m, __shfl_xor(m, off));
        mx[r] = m;
    }
    if (ln == 0) {
#pragma unroll
        for (int r = 0; r < 4; ++r) redm[w][qq * 4 + r] = mx[r];
    }
    __syncthreads();
#pragma unroll
    for (int r = 0; r < 4; ++r) {
        int row = qq * 4 + r;
        mx[r] = fmaxf(fmaxf(redm[0][row], redm[1][row]),
                      fmaxf(redm[2][row], redm[3][row]));
    }

    // exp + row sums
    float rs[4] = {0.0f, 0.0f, 0.0f, 0.0f};
#pragma unroll
    for (int j = 0; j < 16; ++j)
#pragma unroll
        for (int r = 0; r < 4; ++r) {
            float p = __expf((sacc[j][r] - mx[r]) * SCALE);
            sacc[j][r] = p;
            rs[r] += p;
        }
#pragma unroll
    for (int r = 0; r < 4; ++r)
#pragma unroll
        for (int off = 1; off < 16; off <<= 1) rs[r] += __shfl_xor(rs[r], off);
    if (ln == 0) {
#pragma unroll
        for (int r = 0; r < 4; ++r) reds[w][qq * 4 + r] = rs[r];
    }
    __syncthreads();
    float inv[4];
#pragma unroll
    for (int r = 0; r < 4; ++r) {
        int row = qq * 4 + r;
        inv[r] = 1.0f / (reds[0][row] + reds[1][row] + reds[2][row] + reds[3][row]);
    }

    // write exact wei (fp32, from registers) + normalized P (bf16) to LDS
    float* wbase = wei + ((size_t)bh << 20) + (size_t)t0 * T_ + w * 256 + ln;
#pragma unroll
    for (int r = 0; r < 4; ++r) {
        int row = qq * 4 + r;
        float* wr = wbase + (size_t)row * T_;
        bf16_t* pr = &Ps[row * 1032 + w * 256 + ln];
#pragma unroll
        for (int j = 0; j < 16; ++j) {
            float p = sacc[j][r] * inv[r];
            wr[j * 16] = p;
            pr[j * 16] = (bf16_t)p;
        }
    }
    __syncthreads();

    // O = P V : A = Ps (A-layout), B = vt rows (d -> n=ln), direct global loads
    f32x4 oacc = {};
    const bf16_t* vp = vt + (size_t)bh * (D_ * T_) + (size_t)(w * 16 + ln) * T_ + qq * 8;
#pragma unroll
    for (int ks = 0; ks < 32; ++ks) {
        bf16x8 a = *reinterpret_cast<const bf16x8*>(&Ps[ln * 1032 + ks * 32 + qq * 8]);
        bf16x8 bv = *reinterpret_cast<const bf16x8*>(vp + ks * 32);
        oacc = mfma16(a, bv, oacc);
    }
#pragma unroll
    for (int r = 0; r < 4; ++r) {
        int trow = t0 + qq * 4 + r;
        attn[((size_t)b * T_ + trow) * C_ + h * D_ + w * 16 + ln] = (bf16_t)oacc[r];
    }
}

// ---------------------------------------------------------------- layernorm
// out = LN(a_row + b_row) * g + beta ; writes fp32 (+optional bf16 copy)
__global__ __launch_bounds__(256) void k_ln(const float* __restrict__ a,
                                            const float* __restrict__ bsrc,
                                            const float* __restrict__ g,
                                            const float* __restrict__ beta,
                                            float* __restrict__ of,
                                            bf16_t* __restrict__ ob) {
    int row = blockIdx.x;
    int tid = threadIdx.x;
    const float* pa = a + (size_t)row * C_;
    const float* pb = bsrc + (size_t)row * C_;
    float v[3];
    float s = 0.0f, s2 = 0.0f;
#pragma unroll
    for (int u = 0; u < 3; ++u) {
        int c = tid + u * 256;
        v[u] = pa[c] + pb[c];
        s += v[u];
        s2 += v[u] * v[u];
    }
#pragma unroll
    for (int off = 32; off; off >>= 1) {
        s += __shfl_down(s, off);
        s2 += __shfl_down(s2, off);
    }
    __shared__ float ws[4], ws2[4];
    if ((tid & 63) == 0) { ws[tid >> 6] = s; ws2[tid >> 6] = s2; }
    __syncthreads();
    s = ws[0] + ws[1] + ws[2] + ws[3];
    s2 = ws2[0] + ws2[1] + ws2[2] + ws2[3];
    float mu = s * (1.0f / C_);
    float var = s2 * (1.0f / C_) - mu * mu;
    float ri = rsqrtf(var + 1e-5f);
#pragma unroll
    for (int u = 0; u < 3; ++u) {
        int c = tid + u * 256;
        float y = (v[u] - mu) * ri * g[c] + beta[c];
        of[(size_t)row * C_ + c] = y;
        if (ob) ob[(size_t)row * C_ + c] = (bf16_t)y;
    }
}

// ---------------------------------------------------------------- launch
extern "C" void kernel_launch(void* const* d_in, const int* in_sizes, int n_in,
                              void* d_out, int out_size, void* d_ws, size_t ws_size,
                              hipStream_t stream) {
    const float* x     = (const float*)d_in[0];
    const float* Wq    = (const float*)d_in[1];
    const float* Wk    = (const float*)d_in[2];
    const float* Wv    = (const float*)d_in[3];
    const float* Wproj = (const float*)d_in[4];
    const float* bproj = (const float*)d_in[5];
    const float* ln1g  = (const float*)d_in[6];
    const float* ln1b  = (const float*)d_in[7];
    const float* W1    = (const float*)d_in[8];
    const float* b1    = (const float*)d_in[9];
    const float* W2    = (const float*)d_in[10];
    const float* b2    = (const float*)d_in[11];
    const float* ln2g  = (const float*)d_in[12];
    const float* ln2b  = (const float*)d_in[13];

    char* ws = (char*)d_ws;
    bf16_t* xb     = (bf16_t*)(ws + 0);            // 12,582,912
    bf16_t* wqkvt  = (bf16_t*)(ws + 12582912);     //  3,538,944
    bf16_t* qbuf   = (bf16_t*)(ws + 16121856);     // 12,582,912
    bf16_t* kbuf   = (bf16_t*)(ws + 28704768);     // 12,582,912
    bf16_t* vtb    = (bf16_t*)(ws + 41287680);     // 12,582,912
    bf16_t* attnb  = (bf16_t*)(ws + 53870592);     // 12,582,912
    bf16_t* wprojt = (bf16_t*)(ws + 66453504);     //  1,179,648
    float*  projb  = (float*)(ws + 67633152);      // 25,165,824
    float*  hbuf   = (float*)(ws + 92798976);      // 25,165,824
    bf16_t* hidb   = (bf16_t*)(ws + 117964800);    //  2,097,152
    bf16_t* w1t    = (bf16_t*)(ws + 120061952);    //    196,608
    bf16_t* w2t    = (bf16_t*)(ws + 120258560);    //    196,608
    bf16_t* hbb    = xb;     // bf16 copy of h (xb dead after QKV GEMMs)
    float*  ffb    = projb;  // ff output (proj dead after LN1)

    float* wei = (float*)d_out;
    float* y   = (float*)d_out + WEI_ELEMS;

    k_cast_x<<<6144, 256, 0, stream>>>(x, xb);
    k_pack_qkv<<<6912, 256, 0, stream>>>(Wq, Wk, Wv, wqkvt);
    k_pack_proj<<<2304, 256, 0, stream>>>(Wproj, wprojt);
    k_pack_w1<<<384, 256, 0, stream>>>(W1, w1t);
    k_pack_w2<<<384, 256, 0, stream>>>(W2, w2t);

    k_gemm_qk<<<dim3(12, 64), 256, 0, stream>>>(xb, wqkvt, qbuf, kbuf);
    k_gemm_vt<<<dim3(64, 6), 256, 0, stream>>>(wqkvt + (size_t)1536 * C_, xb, vtb);

    k_attn<<<dim3(64, 96), 256, 0, stream>>>(qbuf, kbuf, vtb, wei, attnb);

    k_gemm_proj<<<dim3(6, 64), 256, 0, stream>>>(attnb, wprojt, bproj, projb);
    k_ln<<<8192, 256, 0, stream>>>(x, projb, ln1g, ln1b, hbuf, hbb);
    k_gemm_ff1<<<dim3(1, 64), 256, 0, stream>>>(hbb, w1t, b1, hidb);
    k_gemm_ff2<<<dim3(6, 64), 256, 0, stream>>>(hidb, w2t, b2, ffb);
    k_ln<<<8192, 256, 0, stream>>>(hbuf, ffb, ln2g, ln2b, y, (bf16_t*)nullptr);

    (void)in_sizes; (void)n_in; (void)out_size; (void)ws_size;
}